// Round 4
// baseline (338.318 us; speedup 1.0000x reference)
//
#include <hip/hip_runtime.h>
#include <stdint.h>

typedef __attribute__((ext_vector_type(8))) short short8;
typedef __attribute__((ext_vector_type(4))) float floatx4;

#define DONE_MAGIC 0x600DF00Du

// ---------------- common helpers ----------------

__device__ __forceinline__ float sigm(float x) { return 1.0f / (1.0f + expf(-x)); }

// precise voc (libm) — only in k3 table build (once per node)
__device__ __forceinline__ float vocf(float s) {
  const float V_L = -1.59614486f, V_0 = 4.13646328f;
  const float GAM = 0.63726463f, ALP = 1.40174122f, BET = 2.54478965f;
  return V_L + (V_0 - V_L) * expf(GAM * (s - 1.0f)) + ALP * V_L * (s - 1.0f)
       + (1.0f - ALP) * V_L * (expf(-BET) - expf(-BET * sqrtf(s)));
}

__device__ __forceinline__ unsigned short f2bf(float f) {
  unsigned u = __float_as_uint(f);
  u += 0x7FFFu + ((u >> 16) & 1u);
  return (unsigned short)(u >> 16);
}
__device__ __forceinline__ float bf2f(unsigned short b) {
  return __uint_as_float(((unsigned)b) << 16);
}

// coefficient-form cubic: per cell j (31 cells/row), V = ((c3*u+c2)*u+c1)*u+c0
__device__ __forceinline__ float interp_c(const float* ctab, float s) {
  float f = s * 31.0f;
  float jf = fminf(floorf(f), 30.0f);
  int j = (int)jf;
  float u = f - jf;
  const float4 c = *(const float4*)&ctab[j * 4];
  return fmaf(fmaf(fmaf(c.w, u, c.z), u, c.y), u, c.x);
}

// largest integer s with fl(u+s) <= fl(c*1024).  Single correction each way.
__device__ __forceinline__ int send_bl(float c, float u) {
  float C = c * 1024.0f;
  float sf = floorf(C - u);
  sf += (u + (sf + 1.0f) <= C) ? 1.0f : 0.0f;
  sf -= (u + sf > C) ? 1.0f : 0.0f;
  return (int)sf;
}

__device__ __forceinline__ float fast_exp2(float x) {
  float r;
  asm("v_exp_f32 %0, %1" : "=v"(r) : "v"(x));
  return r;
}

// ---------------- DPP cross-lane (validated bit-exact in earlier rounds) ----------------

template<int C, int RM>
__device__ __forceinline__ float dpp_add_f(float x) {
  return __int_as_float(__builtin_amdgcn_update_dpp(0, __float_as_int(x), C, RM, 0xF, false));
}
template<int C, int RM>
__device__ __forceinline__ float dpp_old_f(float x) {
  return __int_as_float(__builtin_amdgcn_update_dpp(__float_as_int(x), __float_as_int(x), C, RM, 0xF, false));
}
template<int C, int RM>
__device__ __forceinline__ int dpp_old_i(int x) {
  return __builtin_amdgcn_update_dpp(x, x, C, RM, 0xF, false);
}
__device__ __forceinline__ float dpp_wshr1_f0(float x) {     // lane0 := 0
  return __int_as_float(__builtin_amdgcn_update_dpp(0, __float_as_int(x), 0x138, 0xF, 0xF, true));
}
__device__ __forceinline__ int dpp_wshr1_i(int x, int old) { // lane0 := old
  return __builtin_amdgcn_update_dpp(old, x, 0x138, 0xF, 0xF, false);
}
__device__ __forceinline__ int dpp_wshl1_i(int x, int old) { // lane l := lane l+1; lane63 := old
  return __builtin_amdgcn_update_dpp(old, x, 0x130, 0xF, 0xF, false);
}

__device__ __forceinline__ float wave_iscan_add(float x) {
  x += dpp_add_f<0x111, 0xF>(x);
  x += dpp_add_f<0x112, 0xF>(x);
  x += dpp_add_f<0x114, 0xF>(x);
  x += dpp_add_f<0x118, 0xF>(x);
  x += dpp_add_f<0x142, 0xA>(x);
  x += dpp_add_f<0x143, 0xC>(x);
  return x;
}
// full-wave max broadcast to all lanes
__device__ __forceinline__ float wave_max_bcast(float x) {
  x = fmaxf(x, dpp_old_f<0xB1,  0xF>(x));
  x = fmaxf(x, dpp_old_f<0x4E,  0xF>(x));
  x = fmaxf(x, dpp_old_f<0x141, 0xF>(x));
  x = fmaxf(x, dpp_old_f<0x140, 0xF>(x));
  x = fmaxf(x, dpp_old_f<0x142, 0xA>(x));
  x = fmaxf(x, dpp_old_f<0x143, 0xC>(x));
  return __int_as_float(__builtin_amdgcn_readlane(__float_as_int(x), 63));
}
__device__ __forceinline__ int wave_iscan_max(int x) {
  x = max(x, dpp_old_i<0x111, 0xF>(x));
  x = max(x, dpp_old_i<0x112, 0xF>(x));
  x = max(x, dpp_old_i<0x114, 0xF>(x));
  x = max(x, dpp_old_i<0x118, 0xF>(x));
  x = max(x, dpp_old_i<0x142, 0xA>(x));
  x = max(x, dpp_old_i<0x143, 0xC>(x));
  return x;
}

__device__ __forceinline__ float rdlane_f(float x, int lane) {
  return __int_as_float(__builtin_amdgcn_readlane(__float_as_int(x), lane));
}

// lgkmcnt-only barrier: makes prior LDS writes visible without draining
// vmcnt (keeps noise prefetch + vout/sout stores in flight across barriers).
__device__ __forceinline__ void bar_lds() {
  asm volatile("s_waitcnt lgkmcnt(0)" ::: "memory");
  __builtin_amdgcn_s_barrier();
  asm volatile("" ::: "memory");
}

// ---------------- K1: swizzle W2 into hi/lo split-bf16 MFMA B-fragment planes ----------------

__global__ void __launch_bounds__(256)
k1_swizzle(const float* __restrict__ W2g, short* __restrict__ w2hiG, short* __restrict__ w2loG)
{
  int bid = blockIdx.x, tid = threadIdx.x;
  int pg = bid & 15, ng = bid >> 4;
  int u = pg * 256 + tid;
  int kb = u >> 7, l = u & 63, nt = (u >> 6) & 1, kq = l >> 4;
  int col = ng * 32 + nt * 16 + (l & 15);
  short8 hi8, lo8;
  #pragma unroll
  for (int j = 0; j < 8; j++) {
    int k = kb * 32 + kq * 8 + j;
    float w = W2g[k * 512 + col];
    unsigned short h = f2bf(w);
    hi8[j] = (short)h;
    lo8[j] = (short)f2bf(w - bf2f(h));
  }
  size_t off = ((size_t)ng * 4096 + u) * 8;
  *(short8*)(w2hiG + off) = hi8;
  *(short8*)(w2loG + off) = lo8;
}

// ---------------- K2: batched table GEMM (unchanged) ----------------

__global__ void __launch_bounds__(256)
k2_gemm(const float* __restrict__ curg, const float* __restrict__ W1g,
        const float* __restrict__ b1g, const float* __restrict__ b2g,
        const float* __restrict__ W3g, const short* __restrict__ w2hiG,
        const short* __restrict__ w2loG, float* __restrict__ part)
{
  __shared__ short w2S[32768];
  __shared__ float b2S[32], w3S[32];

  const int tid = threadIdx.x, bid = blockIdx.x;
  const int ng = bid & 15, rtg = bid >> 4;
  const int wv = tid >> 6, ln = tid & 63;
  const int kq = ln >> 4;

  {
    const short* srcH = w2hiG + (size_t)ng * 32768;
    for (int i = tid; i < 4096; i += 256)
      *(short8*)(w2S + i * 8) = *(const short8*)(srcH + i * 8);
    if (tid < 32) { b2S[tid] = b2g[ng * 32 + tid]; w3S[tid] = W3g[ng * 32 + tid]; }
  }
  __syncthreads();

  const short* loG = w2loG + (size_t)ng * 32768;
  const int c = ln & 15, q = ln >> 4;
  const float b20 = b2S[c], b21 = b2S[16 + c];
  const float w30 = w3S[c], w31 = w3S[16 + c];

  for (int jj = 0; jj < 3; jj++) {
    int rt = rtg + 32 * jj;
    if (rt >= 72) break;
    int pt = rt * 4 + wv;
    unsigned r = pt * 16 + (ln & 15);
    unsigned t = r / 36u;
    int i = (int)(r - t * 36u);
    float soc = (float)(i - 1) * (1.0f / 31.0f);
    float sI = (curg[t] + 2.0f) / 6.0f;

    floatx4 acc0 = {0.f, 0.f, 0.f, 0.f};
    floatx4 acc1 = {0.f, 0.f, 0.f, 0.f};

    for (int kb = 0; kb < 32; kb++) {
      int k0 = kb * 32 + kq * 8;
      floatx4 wa0 = *(const floatx4*)(W1g + k0);
      floatx4 wa1 = *(const floatx4*)(W1g + k0 + 4);
      floatx4 wb0 = *(const floatx4*)(W1g + 1024 + k0);
      floatx4 wb1 = *(const floatx4*)(W1g + 1024 + k0 + 4);
      floatx4 bb0 = *(const floatx4*)(b1g + k0);
      floatx4 bb1 = *(const floatx4*)(b1g + k0 + 4);
      short8 ah, al;
      #pragma unroll
      for (int j = 0; j < 4; j++) {
        float x = soc * wa0[j] + sI * wb0[j] + bb0[j];
        float z = __builtin_amdgcn_rcpf(1.0f + __expf(-x));
        unsigned short h = f2bf(z);
        ah[j] = (short)h;
        al[j] = (short)f2bf(z - bf2f(h));
      }
      #pragma unroll
      for (int j = 0; j < 4; j++) {
        float x = soc * wa1[j] + sI * wb1[j] + bb1[j];
        float z = __builtin_amdgcn_rcpf(1.0f + __expf(-x));
        unsigned short h = f2bf(z);
        ah[4 + j] = (short)h;
        al[4 + j] = (short)f2bf(z - bf2f(h));
      }
      short8 bh0 = *(const short8*)(w2S + (kb * 2 + 0) * 512 + ln * 8);
      short8 bh1 = *(const short8*)(w2S + (kb * 2 + 1) * 512 + ln * 8);
      short8 bl0 = *(const short8*)(loG + (kb * 2 + 0) * 512 + ln * 8);
      short8 bl1 = *(const short8*)(loG + (kb * 2 + 1) * 512 + ln * 8);
      acc0 = __builtin_amdgcn_mfma_f32_16x16x32_bf16(ah, bh0, acc0, 0, 0, 0);
      acc1 = __builtin_amdgcn_mfma_f32_16x16x32_bf16(ah, bh1, acc1, 0, 0, 0);
      acc0 = __builtin_amdgcn_mfma_f32_16x16x32_bf16(ah, bl0, acc0, 0, 0, 0);
      acc1 = __builtin_amdgcn_mfma_f32_16x16x32_bf16(ah, bl1, acc1, 0, 0, 0);
      acc0 = __builtin_amdgcn_mfma_f32_16x16x32_bf16(al, bh0, acc0, 0, 0, 0);
      acc1 = __builtin_amdgcn_mfma_f32_16x16x32_bf16(al, bh1, acc1, 0, 0, 0);
    }

    #pragma unroll
    for (int r2 = 0; r2 < 4; r2++) {
      float v = w30 * sigm(acc0[r2] + b20) + w31 * sigm(acc1[r2] + b21);
      v += __shfl_xor(v, 1);
      v += __shfl_xor(v, 2);
      v += __shfl_xor(v, 4);
      v += __shfl_xor(v, 8);
      if (c == 0) part[(size_t)(pt * 16 + q * 4 + r2) * 16 + ng] = v;
    }
  }
}

// ---------------- K3a: reduce ng-partials -> fused node values ----------------

__global__ void __launch_bounds__(256)
k3_table(const float* __restrict__ part, const float* __restrict__ b3g,
         const float* __restrict__ curg, float* __restrict__ VtabG)
{
  unsigned r = blockIdx.x * 256 + threadIdx.x;
  if (r < 4608) {
    const float* p = part + (size_t)r * 16;
    float s = 0.f;
    #pragma unroll
    for (int i = 0; i < 16; i++) s += p[i];
    float Z = s + b3g[0];
    unsigned t = r / 36u;
    int i = (int)(r - t * 36u);
    float node = (float)(i - 1) * (1.0f / 31.0f);
    float nodc = fmaxf(node, 1e-10f);
    VtabG[r] = vocf(nodc) - curg[t] * Z;
  }
}

// ---------------- K3b: node values -> per-cell Horner coefficients ----------------

__global__ void __launch_bounds__(256)
k3b_coeff(const float* __restrict__ VtabG, float* __restrict__ ctabG)
{
  int idx = blockIdx.x * 256 + threadIdx.x;   // t*31 + j
  if (idx < 3968) {
    int t = idx / 31, j = idx - t * 31;
    const float* nb = VtabG + t * 36 + j;
    float n0 = nb[0], n1 = nb[1], n2 = nb[2], n3 = nb[3];
    float c0 = n1;
    float c1 = (-2.0f * n0 - 3.0f * n1 + 6.0f * n2 - n3) * (1.0f / 6.0f);
    float c2 = (n0 - 2.0f * n1 + n2) * 0.5f;
    float c3 = (-n0 + 3.0f * (n1 - n2) + n3) * (1.0f / 6.0f);
    *(float4*)&ctabG[idx * 4] = make_float4(c0, c1, c2, c3);
  }
}

// ---------------- K4: 8-wave scan (2 particles/lane), marks resampling, 2 barriers/step ----
// R3 structure ported to 512 threads = 8 waves -> 2 waves/SIMD on block 0's CU:
// one wave's LDS/transcendental stalls are covered by its SIMD partner's issue,
// and per-lane phase work halves (2 interps / 2 exp2 / 2 send_bl / 2 gathers).
//  bar1: merged {wave-max, wave-sum} exchange (8 float2), weights rescaled by
//        2^(m_w - m); bar2: marks + chunkS[8] summaries + pvS visible.
// Swizzle for PPT=2: swz(j) = ((j&1)<<9)|(j>>1); own slots at [tid],[512+tid].
// Blocks 1..255 = DVFS spinners.

__device__ __forceinline__ int swzi(int j) { return ((j & 1) << 9) | (j >> 1); }

__global__ void __launch_bounds__(512)
pf_seq(const float* __restrict__ soc_init, const float* __restrict__ curg,
       const float* __restrict__ vmeasg, const float* __restrict__ noise_g,
       const float* __restrict__ u_g, const float* __restrict__ ctabG,
       float* __restrict__ vout, float* __restrict__ sout, float* __restrict__ outp,
       unsigned* __restrict__ flag)
{
  __shared__ float ctabS[15872];                               // 62 KB coeff table
  __shared__ float2 pvS[2][1024];                              // 16 KB {sp,V1} ping-pong (swizzled)
  __shared__ int   markS[1024] __attribute__((aligned(16)));   // 4 KB (swizzled)
  __shared__ int   chunkS[8] __attribute__((aligned(16)));     // per-128-slot tag max
  __shared__ float2 msS[8] __attribute__((aligned(16)));       // {m_w, s_w}
  __shared__ float lossS[8];

  if (blockIdx.x != 0) {
    // -------- spinner: dependent fma chain + periodic flag poll (DVFS) --------
    float a = 1.0000001f, b = 0.9999999f, c = 0.5f;
    while (__hip_atomic_load(flag, __ATOMIC_RELAXED, __HIP_MEMORY_SCOPE_AGENT) != DONE_MAGIC) {
      #pragma unroll 8
      for (int i = 0; i < 512; i++) { a = fmaf(a, c, b); b = fmaf(b, c, a); }
    }
    asm volatile("" :: "v"(a), "v"(b));
    return;
  }

  const int tid = threadIdx.x;
  const int w = tid >> 6, l = tid & 63;
  const int p0 = tid * 2;                    // first of 2 particles for this thread

  // cooperative ctab load: 3968 float4 across 512 threads
  #pragma unroll
  for (int k = 0; k < 8; k++) {
    int i = tid + 512 * k;
    if (i < 3968) *(float4*)&ctabS[i * 4] = *(const float4*)&ctabG[i * 4];
  }
  float curA = curg[l],   curB = curg[64 + l];
  float vmA  = vmeasg[l], vmB  = vmeasg[64 + l];
  float uA   = u_g[l],    uB   = u_g[64 + l];
  *(int2*)&markS[p0] = make_int2(-1, -1);
  if (tid < 8) chunkS[tid] = -1;

  // prologue: prediction at t=0 uses c_prev = cur[0] -> coeff row 0
  float sp0, sp1;
  {
    float2 s2 = *(const float2*)(soc_init + p0);
    float2 n2 = *(const float2*)(noise_g + p0);
    bar_lds();                                        // ctabS + inits visible
    float c0 = rdlane_f(curA, 0);
    float c02 = c0 * (1.0f / 29000.0f);
    float V00 = interp_c(ctabS, s2.x);
    float V01 = interp_c(ctabS, s2.y);
    sp0 = __builtin_amdgcn_fmed3f(fmaf(n2.x, 0.005f, fmaf(-c02, V00, s2.x)), 1e-10f, 1.0f);
    sp1 = __builtin_amdgcn_fmed3f(fmaf(n2.y, 0.005f, fmaf(-c02, V01, s2.y)), 1e-10f, 1.0f);
  }

  float lossAcc = 0.0f;

  for (int t = 0; t < 128; t++) {
    const float* ctab = ctabS + t * 124;
    const int cb = t & 1;
    float cI, vm, ut;
    if (t < 64) { cI = rdlane_f(curA, t); vm = rdlane_f(vmA, t); ut = rdlane_f(uA, t); }
    else        { cI = rdlane_f(curB, t - 64); vm = rdlane_f(vmB, t - 64); ut = rdlane_f(uB, t - 64); }
    float cI2 = cI * (1.0f / 29000.0f);

    int tn = (t < 127) ? t + 1 : 127;
    float2 noi2 = *(const float2*)(noise_g + tn * 1024 + p0);   // rides across barriers

    // --- A: measurement V1 + swizzled {sp,V1} store + logW (exp2 domain) ---
    float V10 = interp_c(ctab, sp0);
    float V11 = interp_c(ctab, sp1);
    pvS[cb][tid]       = make_float2(sp0, V10);     // swz(p0)   = tid
    pvS[cb][512 + tid] = make_float2(sp1, V11);     // swz(p0+1) = 512+tid
    float d0 = V10 - vm, d1 = V11 - vm;
    float lw0 = d0 * d0 * -7213.4755594f;
    float lw1 = d1 * d1 * -7213.4755594f;

    // --- B: per-wave max + per-wave weight prefix (single exchange) ---
    float mw = wave_max_bcast(fmaxf(lw0, lw1));
    float pr0, pr1, acc;
    {
      float w0 = fast_exp2(lw0 - mw); acc = w0;    pr0 = acc;
      float w1 = fast_exp2(lw1 - mw); acc += w1;   pr1 = acc;
    }
    float isc = wave_iscan_add(acc);
    if (l == 63) msS[w] = make_float2(mw, isc);     // {wave max, wave total}
    bar_lds();                                      // ---- bar1 ----

    float4 msA = *(const float4*)&msS[0];           // {m0,s0,m1,s1}
    float4 msB = *(const float4*)&msS[2];           // {m2,s2,m3,s3}
    float4 msC = *(const float4*)&msS[4];           // {m4,s4,m5,s5}
    float4 msD = *(const float4*)&msS[6];           // {m6,s6,m7,s7}
    float m = fmaxf(fmaxf(fmaxf(msA.x, msA.z), fmaxf(msB.x, msB.z)),
                    fmaxf(fmaxf(msC.x, msC.z), fmaxf(msD.x, msD.z)));
    float f0 = fast_exp2(msA.x - m), f1 = fast_exp2(msA.z - m);
    float f2 = fast_exp2(msB.x - m), f3 = fast_exp2(msB.z - m);
    float f4 = fast_exp2(msC.x - m), f5 = fast_exp2(msC.z - m);
    float f6 = fast_exp2(msD.x - m), f7 = fast_exp2(msD.z - m);
    float t0 = msA.y * f0, t1 = msA.w * f1, t2 = msB.y * f2, t3 = msB.w * f3;
    float t4 = msC.y * f4, t5 = msC.w * f5, t6 = msD.y * f6, t7 = msD.w * f7;
    float total = ((t0 + t1) + (t2 + t3)) + ((t4 + t5) + (t6 + t7));
    float woff = (w > 0 ? t0 : 0.0f) + (w > 1 ? t1 : 0.0f) + (w > 2 ? t2 : 0.0f)
               + (w > 3 ? t3 : 0.0f) + (w > 4 ? t4 : 0.0f) + (w > 5 ? t5 : 0.0f)
               + (w > 6 ? t6 : 0.0f);
    float fw = (w == 0) ? f0 : ((w == 1) ? f1 : ((w == 2) ? f2 : ((w == 3) ? f3 :
               ((w == 4) ? f4 : ((w == 5) ? f5 : ((w == 6) ? f6 : f7))))));
    float exclw = dpp_wshr1_f0(isc);
    float rS = 1.0f / total;

    // --- C: cdf -> se (branchless) ---
    int se0 = send_bl(fmaf(exclw + pr0, fw, woff) * rS, ut);
    int se1 = send_bl(fmaf(exclw + pr1, fw, woff) * rS, ut);

    // --- D: unique-writer marks + chunk summaries ---
    int nxt = dpp_wshl1_i(se0, se1);   // lane l <- lane l+1's se0; lane63 <- own se1 (disables cond path)
    int tbase = t << 10;
    if (tid == 0 && se0 >= 0) { markS[0] = tbase; atomicMax(&chunkS[0], tbase); }
    if (se1 > se0 && se0 < 1023) {
      int s = se0 + 1, tg = tbase | (p0 + 1);
      markS[swzi(s)] = tg; atomicMax(&chunkS[s >> 7], tg);
    }
    if (l != 63) {
      if (nxt > se1 && se1 < 1023) {
        int s = se1 + 1, tg = tbase | (p0 + 2);
        markS[swzi(s)] = tg; atomicMax(&chunkS[s >> 7], tg);
      }
    } else {
      // cross-wave boundary: unconditional max (largest shared-boundary tag wins)
      if (se1 < 1023) {
        int s = se1 + 1;
        int tg = (tid == 511) ? (tbase | 1023) : (tbase | (p0 + 2));
        atomicMax(&markS[swzi(s)], tg); atomicMax(&chunkS[s >> 7], tg);
      }
    }
    bar_lds();                                      // ---- bar2 ----

    // --- E: owner = prefix-max of tags + chunk prefix (no extra barrier) ---
    int mk0 = markS[tid], mk1 = markS[512 + tid];
    int4 chA = *(const int4*)&chunkS[0];
    int4 chB = *(const int4*)&chunkS[4];
    int q0 = mk0;
    int q1 = max(q0, mk1);
    int iscI = wave_iscan_max(q1);
    int ex = dpp_wshr1_i(iscI, -1);
    if (w > 0) ex = max(ex, chA.x);
    if (w > 1) ex = max(ex, chA.y);
    if (w > 2) ex = max(ex, chA.z);
    if (w > 3) ex = max(ex, chA.w);
    if (w > 4) ex = max(ex, chB.x);
    if (w > 5) ex = max(ex, chB.y);
    if (w > 6) ex = max(ex, chB.z);

    int o0 = max(ex, q0) & 1023, o1 = max(ex, q1) & 1023;
    float2 g0 = pvS[cb][swzi(o0)];
    float2 g1 = pvS[cb][swzi(o1)];

    *(float2*)(vout + t * 1024 + p0) = make_float2(g0.y, g1.y);
    *(float2*)(sout + t * 1024 + p0) = make_float2(g0.x, g1.x);

    float e0 = g0.y - vm, e1 = g1.y - vm;
    lossAcc = fmaf(e0, e0, lossAcc);
    lossAcc = fmaf(e1, e1, lossAcc);
    sp0 = __builtin_amdgcn_fmed3f(fmaf(noi2.x, 0.005f, fmaf(-cI2, g0.y, g0.x)), 1e-10f, 1.0f);
    sp1 = __builtin_amdgcn_fmed3f(fmaf(noi2.y, 0.005f, fmaf(-cI2, g1.y, g1.x)), 1e-10f, 1.0f);
  }

  float ls = wave_iscan_add(lossAcc);
  if (l == 63) lossS[w] = ls;
  bar_lds();
  if (tid == 0) {
    float s = ((lossS[0] + lossS[1]) + (lossS[2] + lossS[3]))
            + ((lossS[4] + lossS[5]) + (lossS[6] + lossS[7]));
    outp[0] = s * (1.0f / 131072.0f);
    __hip_atomic_store(flag, DONE_MAGIC, __ATOMIC_RELEASE, __HIP_MEMORY_SCOPE_AGENT);
  }
}

// ---------------- K5: transpose staged outputs to [particle][T] ----------------

__global__ void __launch_bounds__(256)
k5_transpose(const float* __restrict__ vout, const float* __restrict__ sout,
             float* __restrict__ outp)
{
  __shared__ float tile[128 * 65];
  const int bid = blockIdx.x;
  const int arr = bid & 1;
  const int pg = bid >> 1;
  const float* src = arr ? sout : vout;
  float* dst = outp + 1 + arr * 131072;
  const int tid = threadIdx.x;
  const int p0 = pg * 64;

  #pragma unroll 4
  for (int s = 0; s < 32; s++) {
    int t = s * 4 + (tid >> 6);
    int p = tid & 63;
    tile[t * 65 + p] = src[t * 1024 + p0 + p];
  }
  __syncthreads();
  #pragma unroll 4
  for (int s = 0; s < 32; s++) {
    int pl = s * 2 + (tid >> 7);
    int t = tid & 127;
    dst[(p0 + pl) * 128 + t] = tile[t * 65 + pl];
  }
}

// ---------------- launch ----------------

extern "C" void kernel_launch(void* const* d_in, const int* in_sizes, int n_in,
                              void* d_out, int out_size, void* d_ws, size_t ws_size,
                              hipStream_t stream) {
  const float* soc_init = (const float*)d_in[0];
  const float* cur      = (const float*)d_in[1];
  const float* vmeas    = (const float*)d_in[2];
  const float* W1       = (const float*)d_in[3];
  const float* b1       = (const float*)d_in[4];
  const float* W2       = (const float*)d_in[5];
  const float* b2       = (const float*)d_in[6];
  const float* W3       = (const float*)d_in[7];
  const float* b3       = (const float*)d_in[8];
  const float* noise    = (const float*)d_in[9];
  const float* u        = (const float*)d_in[10];
  float* out = (float*)d_out;
  char* ws = (char*)d_ws;

  short* w2hi   = (short*)ws;                                   // 1 MB
  short* w2lo   = (short*)(ws + (1 << 20));                     // 1 MB
  float* part   = (float*)(ws + (2 << 20));                     // 288 KB
  char*  p3     = ws + (2 << 20) + 4608 * 16 * 4;
  float* VtabG  = (float*)p3;                                   // 18.4 KB
  float* ctabG  = (float*)(p3 + 4608 * 4);                      // 62 KB
  float* vout   = (float*)(p3 + 4608 * 4 + 3968 * 16);          // 512 KB
  float* sout   = (float*)(p3 + 4608 * 4 + 3968 * 16 + 1024 * 128 * 4);
  unsigned* flag = (unsigned*)(p3 + 4608 * 4 + 3968 * 16 + 2 * 1024 * 128 * 4);

  k1_swizzle<<<256, 256, 0, stream>>>(W2, w2hi, w2lo);
  k2_gemm<<<512, 256, 0, stream>>>(cur, W1, b1, b2, W3, w2hi, w2lo, part);
  k3_table<<<18, 256, 0, stream>>>(part, b3, cur, VtabG);
  k3b_coeff<<<16, 256, 0, stream>>>(VtabG, ctabG);
  pf_seq<<<256, 512, 0, stream>>>(soc_init, cur, vmeas, noise, u, ctabG, vout, sout, out, flag);
  k5_transpose<<<32, 256, 0, stream>>>(vout, sout, out);
}

// Round 5
// 325.395 us; speedup vs baseline: 1.0397x; 1.0397x over previous
//
#include <hip/hip_runtime.h>
#include <stdint.h>

typedef __attribute__((ext_vector_type(8))) short short8;
typedef __attribute__((ext_vector_type(4))) float floatx4;

#define DONE_MAGIC 0x600DF00Du

// ---------------- common helpers ----------------

__device__ __forceinline__ float sigm(float x) { return 1.0f / (1.0f + expf(-x)); }

// precise voc (libm) — only in k3 table build (once per node)
__device__ __forceinline__ float vocf(float s) {
  const float V_L = -1.59614486f, V_0 = 4.13646328f;
  const float GAM = 0.63726463f, ALP = 1.40174122f, BET = 2.54478965f;
  return V_L + (V_0 - V_L) * expf(GAM * (s - 1.0f)) + ALP * V_L * (s - 1.0f)
       + (1.0f - ALP) * V_L * (expf(-BET) - expf(-BET * sqrtf(s)));
}

__device__ __forceinline__ unsigned short f2bf(float f) {
  unsigned u = __float_as_uint(f);
  u += 0x7FFFu + ((u >> 16) & 1u);
  return (unsigned short)(u >> 16);
}
__device__ __forceinline__ float bf2f(unsigned short b) {
  return __uint_as_float(((unsigned)b) << 16);
}

// coefficient-form cubic: per cell j (31 cells/row), V = ((c3*u+c2)*u+c1)*u+c0
__device__ __forceinline__ float interp_c(const float* ctab, float s) {
  float f = s * 31.0f;
  float jf = fminf(floorf(f), 30.0f);
  int j = (int)jf;
  float u = f - jf;
  const float4 c = *(const float4*)&ctab[j * 4];
  return fmaf(fmaf(fmaf(c.w, u, c.z), u, c.y), u, c.x);
}

// largest integer s with fl(u+s) <= fl(c*1024).  Single correction each way.
__device__ __forceinline__ int send_bl(float c, float u) {
  float C = c * 1024.0f;
  float sf = floorf(C - u);
  sf += (u + (sf + 1.0f) <= C) ? 1.0f : 0.0f;
  sf -= (u + sf > C) ? 1.0f : 0.0f;
  return (int)sf;
}

__device__ __forceinline__ float fast_exp2(float x) {
  float r;
  asm("v_exp_f32 %0, %1" : "=v"(r) : "v"(x));
  return r;
}

// ---------------- DPP cross-lane (validated bit-exact in earlier rounds) ----------------

template<int C, int RM>
__device__ __forceinline__ float dpp_add_f(float x) {
  return __int_as_float(__builtin_amdgcn_update_dpp(0, __float_as_int(x), C, RM, 0xF, false));
}
template<int C, int RM>
__device__ __forceinline__ float dpp_old_f(float x) {
  return __int_as_float(__builtin_amdgcn_update_dpp(__float_as_int(x), __float_as_int(x), C, RM, 0xF, false));
}
template<int C, int RM>
__device__ __forceinline__ int dpp_old_i(int x) {
  return __builtin_amdgcn_update_dpp(x, x, C, RM, 0xF, false);
}
__device__ __forceinline__ float dpp_wshr1_f0(float x) {     // lane0 := 0
  return __int_as_float(__builtin_amdgcn_update_dpp(0, __float_as_int(x), 0x138, 0xF, 0xF, true));
}
__device__ __forceinline__ int dpp_wshr1_i(int x, int old) { // lane0 := old
  return __builtin_amdgcn_update_dpp(old, x, 0x138, 0xF, 0xF, false);
}
__device__ __forceinline__ int dpp_wshl1_i(int x, int old) { // lane l := lane l+1; lane63 := old
  return __builtin_amdgcn_update_dpp(old, x, 0x130, 0xF, 0xF, false);
}

__device__ __forceinline__ float wave_iscan_add(float x) {
  x += dpp_add_f<0x111, 0xF>(x);
  x += dpp_add_f<0x112, 0xF>(x);
  x += dpp_add_f<0x114, 0xF>(x);
  x += dpp_add_f<0x118, 0xF>(x);
  x += dpp_add_f<0x142, 0xA>(x);
  x += dpp_add_f<0x143, 0xC>(x);
  return x;
}
// full-wave max broadcast to all lanes
__device__ __forceinline__ float wave_max_bcast(float x) {
  x = fmaxf(x, dpp_old_f<0xB1,  0xF>(x));
  x = fmaxf(x, dpp_old_f<0x4E,  0xF>(x));
  x = fmaxf(x, dpp_old_f<0x141, 0xF>(x));
  x = fmaxf(x, dpp_old_f<0x140, 0xF>(x));
  x = fmaxf(x, dpp_old_f<0x142, 0xA>(x));
  x = fmaxf(x, dpp_old_f<0x143, 0xC>(x));
  return __int_as_float(__builtin_amdgcn_readlane(__float_as_int(x), 63));
}
__device__ __forceinline__ int wave_iscan_max(int x) {
  x = max(x, dpp_old_i<0x111, 0xF>(x));
  x = max(x, dpp_old_i<0x112, 0xF>(x));
  x = max(x, dpp_old_i<0x114, 0xF>(x));
  x = max(x, dpp_old_i<0x118, 0xF>(x));
  x = max(x, dpp_old_i<0x142, 0xA>(x));
  x = max(x, dpp_old_i<0x143, 0xC>(x));
  return x;
}

__device__ __forceinline__ float rdlane_f(float x, int lane) {
  return __int_as_float(__builtin_amdgcn_readlane(__float_as_int(x), lane));
}

// lgkmcnt-only barrier: makes prior LDS writes visible without draining
// vmcnt (keeps noise prefetch + vout/sout stores in flight across barriers).
__device__ __forceinline__ void bar_lds() {
  asm volatile("s_waitcnt lgkmcnt(0)" ::: "memory");
  __builtin_amdgcn_s_barrier();
  asm volatile("" ::: "memory");
}

// ---------------- K1: swizzle W2 into hi/lo split-bf16 MFMA B-fragment planes ----------------

__global__ void __launch_bounds__(256)
k1_swizzle(const float* __restrict__ W2g, short* __restrict__ w2hiG, short* __restrict__ w2loG)
{
  int bid = blockIdx.x, tid = threadIdx.x;
  int pg = bid & 15, ng = bid >> 4;
  int u = pg * 256 + tid;
  int kb = u >> 7, l = u & 63, nt = (u >> 6) & 1, kq = l >> 4;
  int col = ng * 32 + nt * 16 + (l & 15);
  short8 hi8, lo8;
  #pragma unroll
  for (int j = 0; j < 8; j++) {
    int k = kb * 32 + kq * 8 + j;
    float w = W2g[k * 512 + col];
    unsigned short h = f2bf(w);
    hi8[j] = (short)h;
    lo8[j] = (short)f2bf(w - bf2f(h));
  }
  size_t off = ((size_t)ng * 4096 + u) * 8;
  *(short8*)(w2hiG + off) = hi8;
  *(short8*)(w2loG + off) = lo8;
}

// ---------------- K2: batched table GEMM (unchanged) ----------------

__global__ void __launch_bounds__(256)
k2_gemm(const float* __restrict__ curg, const float* __restrict__ W1g,
        const float* __restrict__ b1g, const float* __restrict__ b2g,
        const float* __restrict__ W3g, const short* __restrict__ w2hiG,
        const short* __restrict__ w2loG, float* __restrict__ part)
{
  __shared__ short w2S[32768];
  __shared__ float b2S[32], w3S[32];

  const int tid = threadIdx.x, bid = blockIdx.x;
  const int ng = bid & 15, rtg = bid >> 4;
  const int wv = tid >> 6, ln = tid & 63;
  const int kq = ln >> 4;

  {
    const short* srcH = w2hiG + (size_t)ng * 32768;
    for (int i = tid; i < 4096; i += 256)
      *(short8*)(w2S + i * 8) = *(const short8*)(srcH + i * 8);
    if (tid < 32) { b2S[tid] = b2g[ng * 32 + tid]; w3S[tid] = W3g[ng * 32 + tid]; }
  }
  __syncthreads();

  const short* loG = w2loG + (size_t)ng * 32768;
  const int c = ln & 15, q = ln >> 4;
  const float b20 = b2S[c], b21 = b2S[16 + c];
  const float w30 = w3S[c], w31 = w3S[16 + c];

  for (int jj = 0; jj < 3; jj++) {
    int rt = rtg + 32 * jj;
    if (rt >= 72) break;
    int pt = rt * 4 + wv;
    unsigned r = pt * 16 + (ln & 15);
    unsigned t = r / 36u;
    int i = (int)(r - t * 36u);
    float soc = (float)(i - 1) * (1.0f / 31.0f);
    float sI = (curg[t] + 2.0f) / 6.0f;

    floatx4 acc0 = {0.f, 0.f, 0.f, 0.f};
    floatx4 acc1 = {0.f, 0.f, 0.f, 0.f};

    for (int kb = 0; kb < 32; kb++) {
      int k0 = kb * 32 + kq * 8;
      floatx4 wa0 = *(const floatx4*)(W1g + k0);
      floatx4 wa1 = *(const floatx4*)(W1g + k0 + 4);
      floatx4 wb0 = *(const floatx4*)(W1g + 1024 + k0);
      floatx4 wb1 = *(const floatx4*)(W1g + 1024 + k0 + 4);
      floatx4 bb0 = *(const floatx4*)(b1g + k0);
      floatx4 bb1 = *(const floatx4*)(b1g + k0 + 4);
      short8 ah, al;
      #pragma unroll
      for (int j = 0; j < 4; j++) {
        float x = soc * wa0[j] + sI * wb0[j] + bb0[j];
        float z = __builtin_amdgcn_rcpf(1.0f + __expf(-x));
        unsigned short h = f2bf(z);
        ah[j] = (short)h;
        al[j] = (short)f2bf(z - bf2f(h));
      }
      #pragma unroll
      for (int j = 0; j < 4; j++) {
        float x = soc * wa1[j] + sI * wb1[j] + bb1[j];
        float z = __builtin_amdgcn_rcpf(1.0f + __expf(-x));
        unsigned short h = f2bf(z);
        ah[4 + j] = (short)h;
        al[4 + j] = (short)f2bf(z - bf2f(h));
      }
      short8 bh0 = *(const short8*)(w2S + (kb * 2 + 0) * 512 + ln * 8);
      short8 bh1 = *(const short8*)(w2S + (kb * 2 + 1) * 512 + ln * 8);
      short8 bl0 = *(const short8*)(loG + (kb * 2 + 0) * 512 + ln * 8);
      short8 bl1 = *(const short8*)(loG + (kb * 2 + 1) * 512 + ln * 8);
      acc0 = __builtin_amdgcn_mfma_f32_16x16x32_bf16(ah, bh0, acc0, 0, 0, 0);
      acc1 = __builtin_amdgcn_mfma_f32_16x16x32_bf16(ah, bh1, acc1, 0, 0, 0);
      acc0 = __builtin_amdgcn_mfma_f32_16x16x32_bf16(ah, bl0, acc0, 0, 0, 0);
      acc1 = __builtin_amdgcn_mfma_f32_16x16x32_bf16(ah, bl1, acc1, 0, 0, 0);
      acc0 = __builtin_amdgcn_mfma_f32_16x16x32_bf16(al, bh0, acc0, 0, 0, 0);
      acc1 = __builtin_amdgcn_mfma_f32_16x16x32_bf16(al, bh1, acc1, 0, 0, 0);
    }

    #pragma unroll
    for (int r2 = 0; r2 < 4; r2++) {
      float v = w30 * sigm(acc0[r2] + b20) + w31 * sigm(acc1[r2] + b21);
      v += __shfl_xor(v, 1);
      v += __shfl_xor(v, 2);
      v += __shfl_xor(v, 4);
      v += __shfl_xor(v, 8);
      if (c == 0) part[(size_t)(pt * 16 + q * 4 + r2) * 16 + ng] = v;
    }
  }
}

// ---------------- K3a: reduce ng-partials -> fused node values ----------------

__global__ void __launch_bounds__(256)
k3_table(const float* __restrict__ part, const float* __restrict__ b3g,
         const float* __restrict__ curg, float* __restrict__ VtabG)
{
  unsigned r = blockIdx.x * 256 + threadIdx.x;
  if (r < 4608) {
    const float* p = part + (size_t)r * 16;
    float s = 0.f;
    #pragma unroll
    for (int i = 0; i < 16; i++) s += p[i];
    float Z = s + b3g[0];
    unsigned t = r / 36u;
    int i = (int)(r - t * 36u);
    float node = (float)(i - 1) * (1.0f / 31.0f);
    float nodc = fmaxf(node, 1e-10f);
    VtabG[r] = vocf(nodc) - curg[t] * Z;
  }
}

// ---------------- K3b: node values -> per-cell Horner coefficients ----------------

__global__ void __launch_bounds__(256)
k3b_coeff(const float* __restrict__ VtabG, float* __restrict__ ctabG)
{
  int idx = blockIdx.x * 256 + threadIdx.x;   // t*31 + j
  if (idx < 3968) {
    int t = idx / 31, j = idx - t * 31;
    const float* nb = VtabG + t * 36 + j;
    float n0 = nb[0], n1 = nb[1], n2 = nb[2], n3 = nb[3];
    float c0 = n1;
    float c1 = (-2.0f * n0 - 3.0f * n1 + 6.0f * n2 - n3) * (1.0f / 6.0f);
    float c2 = (n0 - 2.0f * n1 + n2) * 0.5f;
    float c3 = (-n0 + 3.0f * (n1 - n2) + n3) * (1.0f / 6.0f);
    *(float4*)&ctabG[idx * 4] = make_float4(c0, c1, c2, c3);
  }
}

// ---------------- K4: 4-wave scan (R3 body), SLEEP-POLL spinners ----------------
// pf_seq body identical to R3 (194 us, absmax 0.03515625): 2 lgkmcnt-only
// barriers/step, merged {max,sum} exchange, marks + chunk atomicMax, prefix-max
// gather.  ONLY change: spinner blocks now s_sleep-poll instead of dense FMA.
// Theory: 255 blocks x 256 threads of dependent FMA on all 256 CUs is a
// near-TDP vector load -> power-limited DVFS pins the clock low (~1.0-1.2 GHz,
// inferred from the 2.4x gap between the ~1500-cycle critical-path model and
// the measured 3640 cy/step @2.4GHz assumption).  Sleeping waves keep GRBM
// GUI_ACTIVE asserted (grid resident) at ~zero power -> clock boosts.

__device__ __forceinline__ int swzi(int j) { return ((j & 3) << 8) | (j >> 2); }

__global__ void __launch_bounds__(256)
pf_seq(const float* __restrict__ soc_init, const float* __restrict__ curg,
       const float* __restrict__ vmeasg, const float* __restrict__ noise_g,
       const float* __restrict__ u_g, const float* __restrict__ ctabG,
       float* __restrict__ vout, float* __restrict__ sout, float* __restrict__ outp,
       unsigned* __restrict__ flag)
{
  __shared__ float ctabS[15872];                               // 62 KB coeff table
  __shared__ float2 pvS[2][1024];                              // 16 KB {sp,V1} ping-pong (swizzled)
  __shared__ int   markS[1024] __attribute__((aligned(16)));   // 4 KB (swizzled)
  __shared__ int   chunkS[4] __attribute__((aligned(16)));     // per-256-slot tag max
  __shared__ float2 msS[4] __attribute__((aligned(16)));       // {m_w, s_w}
  __shared__ float lossS[4];

  if (blockIdx.x != 0) {
    // -------- spinner: resident but sleeping; poll flag every ~4k clocks ------
    while (__hip_atomic_load(flag, __ATOMIC_RELAXED, __HIP_MEMORY_SCOPE_AGENT) != DONE_MAGIC) {
      __builtin_amdgcn_s_sleep(64);
    }
    return;
  }

  const int tid = threadIdx.x;
  const int w = tid >> 6, l = tid & 63;
  const int p0 = tid * 4;                    // first of 4 particles for this thread

  // cooperative ctab load: 3968 float4 across 256 threads
  #pragma unroll
  for (int k = 0; k < 16; k++) {
    int i = tid + 256 * k;
    if (i < 3968) *(float4*)&ctabS[i * 4] = *(const float4*)&ctabG[i * 4];
  }
  float curA = curg[l],   curB = curg[64 + l];
  float vmA  = vmeasg[l], vmB  = vmeasg[64 + l];
  float uA   = u_g[l],    uB   = u_g[64 + l];
  *(int4*)&markS[p0] = make_int4(-1, -1, -1, -1);
  if (tid < 4) chunkS[tid] = -1;

  // prologue: prediction at t=0 uses c_prev = cur[0] -> coeff row 0
  float sp0, sp1, sp2, sp3;
  {
    float4 s4 = *(const float4*)(soc_init + p0);
    float4 n4 = *(const float4*)(noise_g + p0);
    bar_lds();                                        // ctabS + inits visible
    float c0 = rdlane_f(curA, 0);
    float c02 = c0 * (1.0f / 29000.0f);
    float spv[4];
    #pragma unroll
    for (int r = 0; r < 4; r++) {
      float si = ((const float*)&s4)[r];
      float V0 = interp_c(ctabS, si);
      float spn = fmaf(((const float*)&n4)[r], 0.005f, fmaf(-c02, V0, si));
      spv[r] = __builtin_amdgcn_fmed3f(spn, 1e-10f, 1.0f);
    }
    sp0 = spv[0]; sp1 = spv[1]; sp2 = spv[2]; sp3 = spv[3];
  }

  float lossAcc = 0.0f;

  for (int t = 0; t < 128; t++) {
    const float* ctab = ctabS + t * 124;
    const int cb = t & 1;
    float cI, vm, ut;
    if (t < 64) { cI = rdlane_f(curA, t); vm = rdlane_f(vmA, t); ut = rdlane_f(uA, t); }
    else        { cI = rdlane_f(curB, t - 64); vm = rdlane_f(vmB, t - 64); ut = rdlane_f(uB, t - 64); }
    float cI2 = cI * (1.0f / 29000.0f);

    int tn = (t < 127) ? t + 1 : 127;
    float4 noi4 = *(const float4*)(noise_g + tn * 1024 + p0);   // rides across barriers

    // --- A: measurement V1 + swizzled {sp,V1} store + logW (exp2 domain) ---
    float V10 = interp_c(ctab, sp0);
    float V11 = interp_c(ctab, sp1);
    float V12 = interp_c(ctab, sp2);
    float V13 = interp_c(ctab, sp3);
    pvS[cb][tid]       = make_float2(sp0, V10);     // swz(p0+r) = r*256+tid
    pvS[cb][256 + tid] = make_float2(sp1, V11);
    pvS[cb][512 + tid] = make_float2(sp2, V12);
    pvS[cb][768 + tid] = make_float2(sp3, V13);
    float d0 = V10 - vm, d1 = V11 - vm, d2 = V12 - vm, d3 = V13 - vm;
    float lw0 = d0 * d0 * -7213.4755594f;
    float lw1 = d1 * d1 * -7213.4755594f;
    float lw2 = d2 * d2 * -7213.4755594f;
    float lw3 = d3 * d3 * -7213.4755594f;

    // --- B: per-wave max + per-wave weight prefix (single exchange) ---
    float lmax = fmaxf(fmaxf(lw0, lw1), fmaxf(lw2, lw3));
    float mw = wave_max_bcast(lmax);
    float pr0, pr1, pr2, pr3, acc;
    {
      float w0 = fast_exp2(lw0 - mw); acc = w0;    pr0 = acc;
      float w1 = fast_exp2(lw1 - mw); acc += w1;   pr1 = acc;
      float w2 = fast_exp2(lw2 - mw); acc += w2;   pr2 = acc;
      float w3 = fast_exp2(lw3 - mw); acc += w3;   pr3 = acc;
    }
    float isc = wave_iscan_add(acc);
    if (l == 63) msS[w] = make_float2(mw, isc);     // {wave max, wave total}
    bar_lds();                                      // ---- bar1 ----

    float4 ms01 = *(const float4*)&msS[0];          // {m0,s0,m1,s1}
    float4 ms23 = *(const float4*)&msS[2];          // {m2,s2,m3,s3}
    float m = fmaxf(fmaxf(ms01.x, ms01.z), fmaxf(ms23.x, ms23.z));
    float f0 = fast_exp2(ms01.x - m), f1 = fast_exp2(ms01.z - m);
    float f2 = fast_exp2(ms23.x - m), f3 = fast_exp2(ms23.z - m);
    float t0 = ms01.y * f0, t1 = ms01.w * f1, t2 = ms23.y * f2, t3 = ms23.w * f3;
    float total = (t0 + t1) + (t2 + t3);
    float woff = (w > 0 ? t0 : 0.0f) + (w > 1 ? t1 : 0.0f) + (w > 2 ? t2 : 0.0f);
    float fw = (w == 0) ? f0 : ((w == 1) ? f1 : ((w == 2) ? f2 : f3));
    float exclw = dpp_wshr1_f0(isc);
    float rS = 1.0f / total;

    // --- C: cdf -> se (branchless) ---
    int se0 = send_bl(fmaf(exclw + pr0, fw, woff) * rS, ut);
    int se1 = send_bl(fmaf(exclw + pr1, fw, woff) * rS, ut);
    int se2 = send_bl(fmaf(exclw + pr2, fw, woff) * rS, ut);
    int se3 = send_bl(fmaf(exclw + pr3, fw, woff) * rS, ut);

    // --- D: unique-writer marks + chunk summaries (no boundary barrier) ---
    int nxt = dpp_wshl1_i(se0, se3);   // lane l <- lane l+1's se0; lane63 <- own se3 (disables cond path)
    int tbase = t << 10;
    if (tid == 0 && se0 >= 0) { markS[0] = tbase; atomicMax(&chunkS[0], tbase); }
    if (se1 > se0 && se0 < 1023) {
      int s = se0 + 1, tg = tbase | (p0 + 1);
      markS[swzi(s)] = tg; atomicMax(&chunkS[s >> 8], tg);
    }
    if (se2 > se1 && se1 < 1023) {
      int s = se1 + 1, tg = tbase | (p0 + 2);
      markS[swzi(s)] = tg; atomicMax(&chunkS[s >> 8], tg);
    }
    if (se3 > se2 && se2 < 1023) {
      int s = se2 + 1, tg = tbase | (p0 + 3);
      markS[swzi(s)] = tg; atomicMax(&chunkS[s >> 8], tg);
    }
    if (l != 63) {
      if (nxt > se3 && se3 < 1023) {
        int s = se3 + 1, tg = tbase | (p0 + 4);
        markS[swzi(s)] = tg; atomicMax(&chunkS[s >> 8], tg);
      }
    } else {
      // cross-wave boundary: unconditional max (largest shared-boundary tag wins)
      if (se3 < 1023) {
        int s = se3 + 1;
        int tg = (tid == 255) ? (tbase | 1023) : (tbase | (p0 + 4));
        atomicMax(&markS[swzi(s)], tg); atomicMax(&chunkS[s >> 8], tg);
      }
    }
    bar_lds();                                      // ---- bar2 ----

    // --- E: owner = prefix-max of tags + chunk prefix (no extra barrier) ---
    int mk0 = markS[tid],       mk1 = markS[256 + tid];
    int mk2 = markS[512 + tid], mk3 = markS[768 + tid];
    int4 ch4 = *(const int4*)chunkS;
    int q0 = mk0;
    int q1 = max(q0, mk1);
    int q2 = max(q1, mk2);
    int q3 = max(q2, mk3);
    int iscI = wave_iscan_max(q3);
    int ex = dpp_wshr1_i(iscI, -1);
    if (w > 0) ex = max(ex, ch4.x);
    if (w > 1) ex = max(ex, ch4.y);
    if (w > 2) ex = max(ex, ch4.z);

    int o0 = max(ex, q0) & 1023, o1 = max(ex, q1) & 1023;
    int o2 = max(ex, q2) & 1023, o3 = max(ex, q3) & 1023;
    float2 g0 = pvS[cb][swzi(o0)];
    float2 g1 = pvS[cb][swzi(o1)];
    float2 g2 = pvS[cb][swzi(o2)];
    float2 g3 = pvS[cb][swzi(o3)];

    *(float4*)(vout + t * 1024 + p0) = make_float4(g0.y, g1.y, g2.y, g3.y);
    *(float4*)(sout + t * 1024 + p0) = make_float4(g0.x, g1.x, g2.x, g3.x);

    float e0 = g0.y - vm, e1 = g1.y - vm, e2 = g2.y - vm, e3 = g3.y - vm;
    lossAcc = fmaf(e0, e0, lossAcc);
    lossAcc = fmaf(e1, e1, lossAcc);
    lossAcc = fmaf(e2, e2, lossAcc);
    lossAcc = fmaf(e3, e3, lossAcc);
    const float* nz = (const float*)&noi4;
    sp0 = __builtin_amdgcn_fmed3f(fmaf(nz[0], 0.005f, fmaf(-cI2, g0.y, g0.x)), 1e-10f, 1.0f);
    sp1 = __builtin_amdgcn_fmed3f(fmaf(nz[1], 0.005f, fmaf(-cI2, g1.y, g1.x)), 1e-10f, 1.0f);
    sp2 = __builtin_amdgcn_fmed3f(fmaf(nz[2], 0.005f, fmaf(-cI2, g2.y, g2.x)), 1e-10f, 1.0f);
    sp3 = __builtin_amdgcn_fmed3f(fmaf(nz[3], 0.005f, fmaf(-cI2, g3.y, g3.x)), 1e-10f, 1.0f);
  }

  float ls = wave_iscan_add(lossAcc);
  if (l == 63) lossS[w] = ls;
  bar_lds();
  if (tid == 0) {
    outp[0] = (lossS[0] + lossS[1] + lossS[2] + lossS[3]) * (1.0f / 131072.0f);
    __hip_atomic_store(flag, DONE_MAGIC, __ATOMIC_RELEASE, __HIP_MEMORY_SCOPE_AGENT);
  }
}

// ---------------- K5: transpose staged outputs to [particle][T] ----------------

__global__ void __launch_bounds__(256)
k5_transpose(const float* __restrict__ vout, const float* __restrict__ sout,
             float* __restrict__ outp)
{
  __shared__ float tile[128 * 65];
  const int bid = blockIdx.x;
  const int arr = bid & 1;
  const int pg = bid >> 1;
  const float* src = arr ? sout : vout;
  float* dst = outp + 1 + arr * 131072;
  const int tid = threadIdx.x;
  const int p0 = pg * 64;

  #pragma unroll 4
  for (int s = 0; s < 32; s++) {
    int t = s * 4 + (tid >> 6);
    int p = tid & 63;
    tile[t * 65 + p] = src[t * 1024 + p0 + p];
  }
  __syncthreads();
  #pragma unroll 4
  for (int s = 0; s < 32; s++) {
    int pl = s * 2 + (tid >> 7);
    int t = tid & 127;
    dst[(p0 + pl) * 128 + t] = tile[t * 65 + pl];
  }
}

// ---------------- launch ----------------

extern "C" void kernel_launch(void* const* d_in, const int* in_sizes, int n_in,
                              void* d_out, int out_size, void* d_ws, size_t ws_size,
                              hipStream_t stream) {
  const float* soc_init = (const float*)d_in[0];
  const float* cur      = (const float*)d_in[1];
  const float* vmeas    = (const float*)d_in[2];
  const float* W1       = (const float*)d_in[3];
  const float* b1       = (const float*)d_in[4];
  const float* W2       = (const float*)d_in[5];
  const float* b2       = (const float*)d_in[6];
  const float* W3       = (const float*)d_in[7];
  const float* b3       = (const float*)d_in[8];
  const float* noise    = (const float*)d_in[9];
  const float* u        = (const float*)d_in[10];
  float* out = (float*)d_out;
  char* ws = (char*)d_ws;

  short* w2hi   = (short*)ws;                                   // 1 MB
  short* w2lo   = (short*)(ws + (1 << 20));                     // 1 MB
  float* part   = (float*)(ws + (2 << 20));                     // 288 KB
  char*  p3     = ws + (2 << 20) + 4608 * 16 * 4;
  float* VtabG  = (float*)p3;                                   // 18.4 KB
  float* ctabG  = (float*)(p3 + 4608 * 4);                      // 62 KB
  float* vout   = (float*)(p3 + 4608 * 4 + 3968 * 16);          // 512 KB
  float* sout   = (float*)(p3 + 4608 * 4 + 3968 * 16 + 1024 * 128 * 4);
  unsigned* flag = (unsigned*)(p3 + 4608 * 4 + 3968 * 16 + 2 * 1024 * 128 * 4);

  k1_swizzle<<<256, 256, 0, stream>>>(W2, w2hi, w2lo);
  k2_gemm<<<512, 256, 0, stream>>>(cur, W1, b1, b2, W3, w2hi, w2lo, part);
  k3_table<<<18, 256, 0, stream>>>(part, b3, cur, VtabG);
  k3b_coeff<<<16, 256, 0, stream>>>(VtabG, ctabG);
  pf_seq<<<256, 256, 0, stream>>>(soc_init, cur, vmeas, noise, u, ctabG, vout, sout, out, flag);
  k5_transpose<<<32, 256, 0, stream>>>(vout, sout, out);
}